// Round 2
// 361.357 us; speedup vs baseline: 1.0183x; 1.0183x over previous
//
#include <hip/hip_runtime.h>

#define PI_F 3.14159265358979323846f
#define TWO_PI_F 6.28318530717958647692f

// model constants (from reference)
#define TAU_F 1.0f
#define TAU_V_F 10.0f
#define TAU_CONN_F 10.0f
#define TAU_E_F 1000.0f
#define GW_F (PI_F / 4.0f)
#define GH_F 3.0f
#define LR_F 10000.0f

#define NUMN 256
#define LB 30
#define SLAB (NUMN * LB)      // 7680 floats per p
#define SLAB4 (SLAB / 4)      // 1920 float4 per p

// clang native vector (works with __builtin_nontemporal_store, unlike HIP float4)
typedef float fx4 __attribute__((ext_vector_type(4)));
typedef float fx2 __attribute__((ext_vector_type(2)));

__device__ __forceinline__ float pbf(float d) {
  // Python: ((d + pi) % (2pi)) - pi  (mod result in [0, 2pi))
  float m = fmodf(d + PI_F, TWO_PI_F);
  if (m < 0.f) m += TWO_PI_F;
  return m - PI_F;
}

// ---------------- K1: sum + argmax of r_hpc ----------------
__global__ __launch_bounds__(256) void k_reduce_hpc(const float* __restrict__ r_hpc,
                                                    int P, float* __restrict__ ws) {
  __shared__ float ssum[256];
  __shared__ float smax[256];
  __shared__ int simax[256];
  int t = threadIdx.x;
  float s = 0.f;
  float bm = -1e30f;
  int bi = 0x7fffffff;
  for (int i = t; i < P; i += 256) {
    float v = r_hpc[i];
    s += v;
    if (v > bm) { bm = v; bi = i; }   // ascending i -> first occurrence per thread
  }
  ssum[t] = s; smax[t] = bm; simax[t] = bi;
  __syncthreads();
  for (int off = 128; off > 0; off >>= 1) {
    if (t < off) {
      ssum[t] += ssum[t + off];
      float vo = smax[t + off]; int io = simax[t + off];
      if (vo > smax[t] || (vo == smax[t] && io < simax[t])) { smax[t] = vo; simax[t] = io; }
    }
    __syncthreads();
  }
  if (t == 0) {
    ws[0] = ssum[0];
    ((int*)ws)[1] = simax[0];
  }
}

// ---------------- K2: barrier-free streaming copy + weighted row-dot partials ----
// Structure: per iteration, handle TWO p's.
//   copy phase : 256 threads stream 3840 float4 (both slabs) in -> out (nontemporal store)
//   dot  phase : thread t owns rows (2*(t&127), 2*(t&127)+1) of slab p + (t>>7).
//                Row pair = 240 B contiguous & 16B-aligned -> 15 float4 loads that
//                hit L1/L2 (just warmed by the copy). No LDS slab, no __syncthreads
//                in the hot loop -> loads for the next iteration overlap the dot.
__global__ __launch_bounds__(256, 3) void k_main(const float* __restrict__ cb,
                                                 const float* __restrict__ r_hpc,
                                                 const float* __restrict__ r_bearing,
                                                 const float* __restrict__ ws_scal,
                                                 float* __restrict__ partial,
                                                 float* __restrict__ out_cb,
                                                 int P, int chunk) {
  __shared__ float pacc[2][NUMN];
  int t = threadIdx.x;
  int blk = blockIdx.x;
  float S = ws_scal[0];

  // r_bearing is uniform -> scalar loads, lives in SGPRs (static indexing only)
  float rbv[LB];
#pragma unroll
  for (int l = 0; l < LB; ++l) rbv[l] = r_bearing[l];

  int which = t >> 7;        // 0: handles p, 1: handles p+1
  int pair  = t & 127;       // row pair index
  int n0 = pair * 2;

  float acc0 = 0.f, acc1 = 0.f, accT = 0.f;

  int p0 = blk * chunk;
  int p1 = p0 + chunk; if (p1 > P) p1 = P;
  int p = p0;
  for (; p + 1 < p1; p += 2) {
    // ---- copy both slabs (coalesced, cold HBM read + nontemporal write) ----
    const fx4* __restrict__ in4 = (const fx4*)(cb + (size_t)p * SLAB);
    fx4* __restrict__ o4 = (fx4*)(out_cb + (size_t)p * SLAB);
#pragma unroll
    for (int k = 0; k < 15; ++k) {           // 2*SLAB4 = 3840 = 15*256
      int i = t + k * 256;
      fx4 tmp = in4[i];
      __builtin_nontemporal_store(tmp, o4 + i);
    }
    // ---- row-pair dot (reads the cache-warm copy of the same bytes) ----
    int pp = p + which;
    float rp = r_hpc[pp];                    // wave-uniform -> s_load
    float w = (rp == 0.f) ? 0.f : rp / S;    // norm_r[pp]
    const fx4* __restrict__ row4 = (const fx4*)(cb + (size_t)pp * SLAB + n0 * LB);
    float d0 = 0.f, d1 = 0.f;
#pragma unroll
    for (int k = 0; k < 15; ++k) {           // 60 floats = rows n0, n0+1
      fx4 vv = row4[k];
      int e = 4 * k;
      if (e + 0 < LB) d0 += vv.x * rbv[e + 0]; else d1 += vv.x * rbv[e + 0 - LB];
      if (e + 1 < LB) d0 += vv.y * rbv[e + 1]; else d1 += vv.y * rbv[e + 1 - LB];
      if (e + 2 < LB) d0 += vv.z * rbv[e + 2]; else d1 += vv.z * rbv[e + 2 - LB];
      if (e + 3 < LB) d0 += vv.w * rbv[e + 3]; else d1 += vv.w * rbv[e + 3 - LB];
    }
    acc0 += w * d0;
    acc1 += w * d1;
  }
  if (p < p1) {
    // tail: single leftover slab; thread t owns row t (float2-aligned, 120 B)
    const fx4* __restrict__ in4 = (const fx4*)(cb + (size_t)p * SLAB);
    fx4* __restrict__ o4 = (fx4*)(out_cb + (size_t)p * SLAB);
    for (int i = t; i < SLAB4; i += 256) {
      fx4 tmp = in4[i];
      __builtin_nontemporal_store(tmp, o4 + i);
    }
    float rp = r_hpc[p];
    float w = (rp == 0.f) ? 0.f : rp / S;
    const fx2* __restrict__ row2 = (const fx2*)(cb + (size_t)p * SLAB + t * LB);
    float d = 0.f;
#pragma unroll
    for (int k = 0; k < 15; ++k) {
      fx2 v2 = row2[k];
      d += v2.x * rbv[2 * k] + v2.y * rbv[2 * k + 1];
    }
    accT = w * d;
  }

  // combine the two p-parity halves (each covers all 256 rows) + tail (row t)
  pacc[which][n0]     = acc0;
  pacc[which][n0 + 1] = acc1;
  __syncthreads();
  partial[(size_t)blk * NUMN + t] = pacc[0][t] + pacc[1][t] + accT;
}

// ---------------- K3: reduce partials [nb][256] -> [64][256] ----------------
__global__ __launch_bounds__(256) void k_reduce_partial(const float* __restrict__ partial,
                                                        float* __restrict__ p2, int nb) {
  int t = threadIdx.x;
  int j = blockIdx.x;  // 64 blocks
  float s = 0.f;
  for (int b = j; b < nb; b += 64) s += partial[(size_t)b * NUMN + t];
  p2[(size_t)j * NUMN + t] = s;
}

__device__ __forceinline__ float block_reduce_sum(float val, float* red, int t) {
  red[t] = val;
  __syncthreads();
  for (int off = 128; off > 0; off >>= 1) {
    if (t < off) red[t] += red[t + off];
    __syncthreads();
  }
  float r0 = red[0];
  __syncthreads();
  return r0;
}

// ---------------- K4: all the small math + index-row rewrite ----------------
__global__ __launch_bounds__(256) void k_finish(
    const float* __restrict__ cb,
    const float* __restrict__ r, const float* __restrict__ u, const float* __restrict__ v,
    const float* __restrict__ noise_hd,
    const float* __restrict__ r_bearing, const float* __restrict__ noise_bearing,
    const float* __restrict__ pos_estimate, const float* __restrict__ angular_velocity,
    const float* __restrict__ sen2HD_stre, const float* __restrict__ shared_t,
    const float* __restrict__ dtp,
    const float* __restrict__ ws_scal, const float* __restrict__ p2,
    float* __restrict__ out) {
  __shared__ float red[256];
  __shared__ float rL[256], connL[256], rhdL[256];
  __shared__ float rbL[32];
  __shared__ float bc[8];
  int t = threadIdx.x;
  int index = ((const int*)ws_scal)[1];

  // input_bearing[t]
  float ib = 0.f;
  for (int j = 0; j < 64; ++j) ib += p2[(size_t)j * NUMN + t];

  float x = -PI_F + (float)t * (TWO_PI_F / 256.f);
  float rt = r[t];
  rL[t] = rt;

  float ssin = block_reduce_sum(sinf(x) * rt, red, t);
  float scos = block_reduce_sum(cosf(x) * rt, red, t);

  if (t == 0) {
    float center = atan2f(ssin, scos);
    float pe = pos_estimate[0];
    float dtv = dtp[0];
    float pos_e = pe + (pbf(center - pe) / TAU_E_F + angular_velocity[0]) * dtv;
    bc[0] = pbf(pos_e);  // pos_est
  }
  __syncthreads();
  float pos_est = bc[0];

  // conn (ring kernel), J0 = 20/256
  {
    float J0 = 20.f / 256.f;
    float dmin = fminf((float)t, 256.f - (float)t) * (TWO_PI_F / 256.f);
    float q = dmin / GW_F;
    connL[t] = J0 * expf(-0.5f * q * q) / (TWO_PI_F * GW_F * GW_F);
  }
  __syncthreads();

  // Irec = circular convolution (== real(ifft(fft(r)*fft(conn))))
  float Irec = 0.f;
  for (int m2 = 0; m2 < 256; ++m2) Irec += rL[m2] * connL[(t - m2) & 255];

  float dd = pbf(x - pos_est);
  float qq = dd / GW_F;
  float Iext = GH_F * expf(-0.25f * qq * qq);

  float input_total = Iext + Irec + ib * sen2HD_stre[0];
  float tstep = shared_t[1] - shared_t[0];
  float e1 = expf(-tstep / TAU_F);
  float e2 = expf(-tstep / TAU_V_F);
  float mcoef = 0.84f * TAU_F / TAU_V_F;

  float ut = u[t], vt = v[t];
  float Cu = input_total - vt;
  float Cv = mcoef * ut;
  float u_sol = Cu + (ut - Cu) * e1;
  float v_sol = Cv + (vt - Cv) * e2;
  float u_new = fmaxf(u_sol, 0.f);
  float r1 = u_new * u_new;
  float s1 = block_reduce_sum(r1, red, t);
  float kcoef = 0.8f / 256.f * 20.f;
  float r_new = r1 / (1.f + kcoef * s1);

  out[t] = r_new;
  out[256 + t] = u_new;
  out[512 + t] = v_sol;

  rhdL[t] = r_new * (1.f + fabsf(noise_hd[t]));
  if (t < LB) rbL[t] = r_bearing[t] + fabsf(noise_bearing[t]);
  __syncthreads();

  if (t == 0) {
    // 4th-largest value of rhdL (value threshold reproduces top_k + >= semantics incl. ties)
    int e0 = -1, e1i = -1, e2i = -1, e3 = -1;
    float thr = 0.f;
    for (int pass = 0; pass < 4; ++pass) {
      float bm = -1e30f; int bi = -1;
      for (int i2 = 0; i2 < 256; ++i2) {
        if (i2 == e0 || i2 == e1i || i2 == e2i || i2 == e3) continue;
        float vv = rhdL[i2];
        if (vv > bm) { bm = vv; bi = i2; }
      }
      if (pass == 0) e0 = bi; else if (pass == 1) e1i = bi; else if (pass == 2) e2i = bi; else e3 = bi;
      thr = bm;
    }
    bc[1] = thr;
  }
  __syncthreads();
  float thr = bc[1];
  float r_learn = (rhdL[t] >= thr) ? rhdL[t] : 0.f;

  float dtv = dtp[0];
  float fac = (LR_F / TAU_CONN_F) * dtv;  // d_b = fac * r_learn * rb * cb0
  const float* rowp = cb + ((size_t)index * NUMN + t) * LB;
  float vals[LB];
  float s = 0.f;
#pragma unroll
  for (int l = 0; l < LB; ++l) {
    float vv = rowp[l] * (1.f + fac * r_learn * rbL[l]);
    vals[l] = vv;
    s += vv;
  }
  float inv = 1.f / s;  // NORM_FAC_HD = 1
  float* orow = out + 768 + ((size_t)index * NUMN + t) * LB;
#pragma unroll
  for (int l = 0; l < LB; ++l) orow[l] = vals[l] * inv;
}

extern "C" void kernel_launch(void* const* d_in, const int* in_sizes, int n_in,
                              void* d_out, int out_size, void* d_ws, size_t ws_size,
                              hipStream_t stream) {
  const float* conn_bearing = (const float*)d_in[0];
  const float* r            = (const float*)d_in[1];
  const float* u            = (const float*)d_in[2];
  const float* v            = (const float*)d_in[3];
  const float* r_hpc        = (const float*)d_in[4];
  const float* r_bearing    = (const float*)d_in[5];
  const float* pos_estimate = (const float*)d_in[6];
  const float* angular_vel  = (const float*)d_in[7];
  // d_in[8] = HD (unused by reference)
  const float* sen2HD       = (const float*)d_in[9];
  const float* shared_t     = (const float*)d_in[10];
  const float* noise_hd     = (const float*)d_in[11];
  const float* noise_bear   = (const float*)d_in[12];
  const float* dtp          = (const float*)d_in[13];

  int P = in_sizes[4];  // 20000

  float* out = (float*)d_out;
  float* ws = (float*)d_ws;

  const int OFF_P2 = 16;                    // floats
  const int OFF_PART = OFF_P2 + 64 * NUMN;  // 16 + 16384

  int nb = 2500;  // chunk = 8 (even -> paired-p fast path, no tail)
  {
    size_t avail = ws_size / 4;
    if (avail < (size_t)OFF_PART + NUMN) {
      nb = 1;  // degenerate fallback
    } else {
      size_t maxnb = (avail - OFF_PART) / NUMN;
      if ((size_t)nb > maxnb) nb = (int)maxnb;
      if (nb < 1) nb = 1;
    }
  }
  int chunk = (P + nb - 1) / nb;

  k_reduce_hpc<<<1, 256, 0, stream>>>(r_hpc, P, ws);
  k_main<<<nb, 256, 0, stream>>>(conn_bearing, r_hpc, r_bearing, ws,
                                 ws + OFF_PART, out + 768, P, chunk);
  k_reduce_partial<<<64, 256, 0, stream>>>(ws + OFF_PART, ws + OFF_P2, nb);
  k_finish<<<1, 256, 0, stream>>>(conn_bearing, r, u, v, noise_hd, r_bearing, noise_bear,
                                  pos_estimate, angular_vel, sen2HD, shared_t, dtp,
                                  ws, ws + OFF_P2, out);
}

// Round 3
// 315.288 us; speedup vs baseline: 1.1671x; 1.1461x over previous
//
#include <hip/hip_runtime.h>

#define PI_F 3.14159265358979323846f
#define TWO_PI_F 6.28318530717958647692f

// model constants (from reference)
#define TAU_F 1.0f
#define TAU_V_F 10.0f
#define TAU_CONN_F 10.0f
#define TAU_E_F 1000.0f
#define GW_F (PI_F / 4.0f)
#define GH_F 3.0f
#define LR_F 10000.0f

#define NUMN 256
#define LB 30
#define SLAB (NUMN * LB)      // 7680 floats per p
#define SLAB4 (SLAB / 4)      // 1920 float4 per p
#define WREG4 480             // float4 per wave region (= SLAB4/4)

// clang native vectors (work with __builtin_nontemporal_*)
typedef float fx4 __attribute__((ext_vector_type(4)));
typedef float fx2 __attribute__((ext_vector_type(2)));

__device__ __forceinline__ float pbf(float d) {
  // Python: ((d + pi) % (2pi)) - pi  (mod result in [0, 2pi))
  float m = fmodf(d + PI_F, TWO_PI_F);
  if (m < 0.f) m += TWO_PI_F;
  return m - PI_F;
}

// ---------------- K1: sum + argmax of r_hpc ----------------
__global__ __launch_bounds__(256) void k_reduce_hpc(const float* __restrict__ r_hpc,
                                                    int P, float* __restrict__ ws) {
  __shared__ float ssum[256];
  __shared__ float smax[256];
  __shared__ int simax[256];
  int t = threadIdx.x;
  float s = 0.f;
  float bm = -1e30f;
  int bi = 0x7fffffff;
  for (int i = t; i < P; i += 256) {
    float v = r_hpc[i];
    s += v;
    if (v > bm) { bm = v; bi = i; }   // ascending i -> first occurrence per thread
  }
  ssum[t] = s; smax[t] = bm; simax[t] = bi;
  __syncthreads();
  for (int off = 128; off > 0; off >>= 1) {
    if (t < off) {
      ssum[t] += ssum[t + off];
      float vo = smax[t + off]; int io = simax[t + off];
      if (vo > smax[t] || (vo == smax[t] && io < simax[t])) { smax[t] = vo; simax[t] = io; }
    }
    __syncthreads();
  }
  if (t == 0) {
    ws[0] = ssum[0];
    ((int*)ws)[1] = simax[0];
  }
}

// ---------------- K2: barrier-free per-wave-region stream + row dot -------------
// One slab = 256 rows x 120 B. Wave w owns bytes [7680w, 7680(w+1)) of every slab
// = exactly rows 64w..64w+63 = exactly the rows its own lanes dot-reduce.
// Per slab, per wave (fully intra-wave, DS pipe is in-order per wave):
//   1. global fx4 loads (coalesced, nontemporal) of own region into VGPRs
//   2. nontemporal store to out  AND  ds_write into own private LDS region
//   3. ds_read own row (120 B) -> 30-term dot with r_bearing -> acc
// No __syncthreads anywhere; no global byte is read twice; single LDS buffer.
__global__ __launch_bounds__(256, 4) void k_main(const float* __restrict__ cb,
                                                 const float* __restrict__ r_hpc,
                                                 const float* __restrict__ r_bearing,
                                                 const float* __restrict__ ws_scal,
                                                 float* __restrict__ partial,
                                                 float* __restrict__ out_cb,
                                                 int P, int chunk) {
  __shared__ __align__(16) float buf[4][SLAB / 4];   // 4 x 7680 B private wave regions
  int t = threadIdx.x;
  int w = t >> 6;          // wave id 0..3
  int lane = t & 63;
  float S = ws_scal[0];

  // r_bearing is uniform -> scalar loads (static indexing only)
  float rbv[LB];
#pragma unroll
  for (int l = 0; l < LB; ++l) rbv[l] = r_bearing[l];

  float* wb = buf[w];
  fx4* wb4 = (fx4*)wb;
  const fx2* row2 = (const fx2*)(wb + lane * LB);   // this lane's 120 B row (15 fx2)

  float acc = 0.f;
  int p0 = blockIdx.x * chunk;
  int p1 = p0 + chunk; if (p1 > P) p1 = P;

  for (int p = p0; p < p1; ++p) {
    size_t base4 = (size_t)p * SLAB4 + (size_t)w * WREG4;  // fx4 index of wave region
    const fx4* __restrict__ in4 = (const fx4*)cb + base4;
    fx4* __restrict__ o4 = (fx4*)out_cb + base4;

    // 7 full-wave 16B chunks + 1 half-wave chunk = 480 fx4 = 7680 B
    fx4 v0 = __builtin_nontemporal_load(in4 + lane);
    fx4 v1 = __builtin_nontemporal_load(in4 + lane + 64);
    fx4 v2 = __builtin_nontemporal_load(in4 + lane + 128);
    fx4 v3 = __builtin_nontemporal_load(in4 + lane + 192);
    fx4 v4 = __builtin_nontemporal_load(in4 + lane + 256);
    fx4 v5 = __builtin_nontemporal_load(in4 + lane + 320);
    fx4 v6 = __builtin_nontemporal_load(in4 + lane + 384);
    fx4 v7;
    if (lane < 32) v7 = __builtin_nontemporal_load(in4 + lane + 448);

    __builtin_nontemporal_store(v0, o4 + lane);       wb4[lane]       = v0;
    __builtin_nontemporal_store(v1, o4 + lane + 64);  wb4[lane + 64]  = v1;
    __builtin_nontemporal_store(v2, o4 + lane + 128); wb4[lane + 128] = v2;
    __builtin_nontemporal_store(v3, o4 + lane + 192); wb4[lane + 192] = v3;
    __builtin_nontemporal_store(v4, o4 + lane + 256); wb4[lane + 256] = v4;
    __builtin_nontemporal_store(v5, o4 + lane + 320); wb4[lane + 320] = v5;
    __builtin_nontemporal_store(v6, o4 + lane + 384); wb4[lane + 384] = v6;
    if (lane < 32) {
      __builtin_nontemporal_store(v7, o4 + lane + 448);
      wb4[lane + 448] = v7;
    }

    // row dot from own LDS region (written above by this wave; DS in-order)
    float rp = r_hpc[p];                  // block-uniform -> scalar load
    float d = 0.f;
#pragma unroll
    for (int k = 0; k < 15; ++k) {
      fx2 u2 = row2[k];
      d += u2.x * rbv[2 * k] + u2.y * rbv[2 * k + 1];
    }
    float wgt = (rp == 0.f) ? 0.f : rp / S;   // norm_r[p]
    acc += wgt * d;
  }

  // thread t accumulated neuron n = t across its slabs
  partial[(size_t)blockIdx.x * NUMN + t] = acc;
}

// ---------------- K3: reduce partials [nb][256] -> [64][256] ----------------
__global__ __launch_bounds__(256) void k_reduce_partial(const float* __restrict__ partial,
                                                        float* __restrict__ p2, int nb) {
  int t = threadIdx.x;
  int j = blockIdx.x;  // 64 blocks
  float s = 0.f;
  for (int b = j; b < nb; b += 64) s += partial[(size_t)b * NUMN + t];
  p2[(size_t)j * NUMN + t] = s;
}

__device__ __forceinline__ float block_reduce_sum(float val, float* red, int t) {
  red[t] = val;
  __syncthreads();
  for (int off = 128; off > 0; off >>= 1) {
    if (t < off) red[t] += red[t + off];
    __syncthreads();
  }
  float r0 = red[0];
  __syncthreads();
  return r0;
}

// ---------------- K4: all the small math + index-row rewrite ----------------
__global__ __launch_bounds__(256) void k_finish(
    const float* __restrict__ cb,
    const float* __restrict__ r, const float* __restrict__ u, const float* __restrict__ v,
    const float* __restrict__ noise_hd,
    const float* __restrict__ r_bearing, const float* __restrict__ noise_bearing,
    const float* __restrict__ pos_estimate, const float* __restrict__ angular_velocity,
    const float* __restrict__ sen2HD_stre, const float* __restrict__ shared_t,
    const float* __restrict__ dtp,
    const float* __restrict__ ws_scal, const float* __restrict__ p2,
    float* __restrict__ out) {
  __shared__ float red[256];
  __shared__ float rL[256], connL[256], rhdL[256];
  __shared__ float rbL[32];
  __shared__ float bc[8];
  int t = threadIdx.x;
  int index = ((const int*)ws_scal)[1];

  // input_bearing[t]
  float ib = 0.f;
  for (int j = 0; j < 64; ++j) ib += p2[(size_t)j * NUMN + t];

  float x = -PI_F + (float)t * (TWO_PI_F / 256.f);
  float rt = r[t];
  rL[t] = rt;

  float ssin = block_reduce_sum(sinf(x) * rt, red, t);
  float scos = block_reduce_sum(cosf(x) * rt, red, t);

  if (t == 0) {
    float center = atan2f(ssin, scos);
    float pe = pos_estimate[0];
    float dtv = dtp[0];
    float pos_e = pe + (pbf(center - pe) / TAU_E_F + angular_velocity[0]) * dtv;
    bc[0] = pbf(pos_e);  // pos_est
  }
  __syncthreads();
  float pos_est = bc[0];

  // conn (ring kernel), J0 = 20/256
  {
    float J0 = 20.f / 256.f;
    float dmin = fminf((float)t, 256.f - (float)t) * (TWO_PI_F / 256.f);
    float q = dmin / GW_F;
    connL[t] = J0 * expf(-0.5f * q * q) / (TWO_PI_F * GW_F * GW_F);
  }
  __syncthreads();

  // Irec = circular convolution (== real(ifft(fft(r)*fft(conn))))
  float Irec = 0.f;
  for (int m2 = 0; m2 < 256; ++m2) Irec += rL[m2] * connL[(t - m2) & 255];

  float dd = pbf(x - pos_est);
  float qq = dd / GW_F;
  float Iext = GH_F * expf(-0.25f * qq * qq);

  float input_total = Iext + Irec + ib * sen2HD_stre[0];
  float tstep = shared_t[1] - shared_t[0];
  float e1 = expf(-tstep / TAU_F);
  float e2 = expf(-tstep / TAU_V_F);
  float mcoef = 0.84f * TAU_F / TAU_V_F;

  float ut = u[t], vt = v[t];
  float Cu = input_total - vt;
  float Cv = mcoef * ut;
  float u_sol = Cu + (ut - Cu) * e1;
  float v_sol = Cv + (vt - Cv) * e2;
  float u_new = fmaxf(u_sol, 0.f);
  float r1 = u_new * u_new;
  float s1 = block_reduce_sum(r1, red, t);
  float kcoef = 0.8f / 256.f * 20.f;
  float r_new = r1 / (1.f + kcoef * s1);

  out[t] = r_new;
  out[256 + t] = u_new;
  out[512 + t] = v_sol;

  rhdL[t] = r_new * (1.f + fabsf(noise_hd[t]));
  if (t < LB) rbL[t] = r_bearing[t] + fabsf(noise_bearing[t]);
  __syncthreads();

  if (t == 0) {
    // 4th-largest value of rhdL (value threshold reproduces top_k + >= semantics incl. ties)
    int e0 = -1, e1i = -1, e2i = -1, e3 = -1;
    float thr = 0.f;
    for (int pass = 0; pass < 4; ++pass) {
      float bm = -1e30f; int bi = -1;
      for (int i2 = 0; i2 < 256; ++i2) {
        if (i2 == e0 || i2 == e1i || i2 == e2i || i2 == e3) continue;
        float vv = rhdL[i2];
        if (vv > bm) { bm = vv; bi = i2; }
      }
      if (pass == 0) e0 = bi; else if (pass == 1) e1i = bi; else if (pass == 2) e2i = bi; else e3 = bi;
      thr = bm;
    }
    bc[1] = thr;
  }
  __syncthreads();
  float thr = bc[1];
  float r_learn = (rhdL[t] >= thr) ? rhdL[t] : 0.f;

  float dtv = dtp[0];
  float fac = (LR_F / TAU_CONN_F) * dtv;  // d_b = fac * r_learn * rb * cb0
  const float* rowp = cb + ((size_t)index * NUMN + t) * LB;
  float vals[LB];
  float s = 0.f;
#pragma unroll
  for (int l = 0; l < LB; ++l) {
    float vv = rowp[l] * (1.f + fac * r_learn * rbL[l]);
    vals[l] = vv;
    s += vv;
  }
  float inv = 1.f / s;  // NORM_FAC_HD = 1
  float* orow = out + 768 + ((size_t)index * NUMN + t) * LB;
#pragma unroll
  for (int l = 0; l < LB; ++l) orow[l] = vals[l] * inv;
}

extern "C" void kernel_launch(void* const* d_in, const int* in_sizes, int n_in,
                              void* d_out, int out_size, void* d_ws, size_t ws_size,
                              hipStream_t stream) {
  const float* conn_bearing = (const float*)d_in[0];
  const float* r            = (const float*)d_in[1];
  const float* u            = (const float*)d_in[2];
  const float* v            = (const float*)d_in[3];
  const float* r_hpc        = (const float*)d_in[4];
  const float* r_bearing    = (const float*)d_in[5];
  const float* pos_estimate = (const float*)d_in[6];
  const float* angular_vel  = (const float*)d_in[7];
  // d_in[8] = HD (unused by reference)
  const float* sen2HD       = (const float*)d_in[9];
  const float* shared_t     = (const float*)d_in[10];
  const float* noise_hd     = (const float*)d_in[11];
  const float* noise_bear   = (const float*)d_in[12];
  const float* dtp          = (const float*)d_in[13];

  int P = in_sizes[4];  // 20000

  float* out = (float*)d_out;
  float* ws = (float*)d_ws;

  const int OFF_P2 = 16;                    // floats
  const int OFF_PART = OFF_P2 + 64 * NUMN;  // 16 + 16384

  // 1250 blocks x chunk 16 = 20000; 5 blocks/CU (30 KB LDS) -> all ~resident
  int nb = 1250;
  {
    size_t avail = ws_size / 4;
    if (avail < (size_t)OFF_PART + NUMN) {
      nb = 1;  // degenerate fallback
    } else {
      size_t maxnb = (avail - OFF_PART) / NUMN;
      if ((size_t)nb > maxnb) nb = (int)maxnb;
      if (nb < 1) nb = 1;
    }
  }
  int chunk = (P + nb - 1) / nb;

  k_reduce_hpc<<<1, 256, 0, stream>>>(r_hpc, P, ws);
  k_main<<<nb, 256, 0, stream>>>(conn_bearing, r_hpc, r_bearing, ws,
                                 ws + OFF_PART, out + 768, P, chunk);
  k_reduce_partial<<<64, 256, 0, stream>>>(ws + OFF_PART, ws + OFF_P2, nb);
  k_finish<<<1, 256, 0, stream>>>(conn_bearing, r, u, v, noise_hd, r_bearing, noise_bear,
                                  pos_estimate, angular_vel, sen2HD, shared_t, dtp,
                                  ws, ws + OFF_P2, out);
}